// Round 14
// baseline (2664.509 us; speedup 1.0000x reference)
//
#include <hip/hip_runtime.h>

// MyRnn: 2-layer SimpleRNN, B=1024 T=80 U=1024 E=100. f32 I/O, f16 MFMA compute.
// v12: REGISTER-RESIDENT WEIGHTS. Unified model fitting v6-v11: dur/step ==
// bytes ISSUED through global_load_lds per CU / ~55 GB/s (issue-side ceiling;
// FETCH_SIZE is memory-side and irrelevant — v10 proved +16MB/iter is free).
// v7 staged ~1.0 MB/CU/step (A+B) = 18 us. Weights are iteration-invariant:
// hold each wave's B-operand as MFMA fragments in VGPRs (16 cols x K=2048 =
// h8v wb[64] = 256 VGPR; 1 block/CU x 8 waves = 2 waves/SIMD -> 512-VGPR
// budget). Tile 64x128, 256 blocks. Per step only A (h-state) is staged:
// 256 KB/CU -> 4x cut. 16 single-barrier chunk rounds (4 buf, 3-ahead).
// Coherence (WT sc0sc1 h-stores, bypass gl_lds h-loads) + hierarchical
// relaxed gsync = v7 verbatim. wb k-mapping verified against v7 swizzle
// algebra: LDS unit read = (kk*4+quad)^(l16&7) XOR staged-swizzle (r&7=l16&7)
// -> logical k = (kk*4+quad)*8 -> wb[ks] = WTrow + ks*32 + quad*8.

typedef _Float16 h8v __attribute__((ext_vector_type(8)));
typedef float    f4v __attribute__((ext_vector_type(4)));
typedef unsigned int u4v __attribute__((ext_vector_type(4)));

#define UNITS 1024
#define SEQ   80
#define EMBD  100
#define EPAD  128
#define KC    128
#define GRID  256

__device__ __forceinline__ float tanh_fast(float x) {
    x = fminf(15.f, fmaxf(-15.f, x));   // also scrubs NaN
    float e = __expf(2.f * x);
    return (e - 1.f) / (e + 1.f);
}

// cacheable global->LDS (EMBP): L1/L2-resident
__device__ __forceinline__ void gl_lds16_c(const _Float16* g, _Float16* l) {
    __builtin_amdgcn_global_load_lds(
        (const __attribute__((address_space(1))) void*)g,
        (__attribute__((address_space(3))) void*)l, 16, 0, 0);
}
// device-coherent bypass global->LDS (h-state): aux = sc0|sc1 = 0x11
__device__ __forceinline__ void gl_lds16_v(const _Float16* g, _Float16* l) {
    __builtin_amdgcn_global_load_lds(
        (const __attribute__((address_space(1))) void*)g,
        (__attribute__((address_space(3))) void*)l, 16, 0, 0x11);
}
// write-through device-coherent 2B store (h-state)
__device__ __forceinline__ void st2_wt(_Float16* p, float v) {
    _Float16 h = (_Float16)v;
    unsigned int uv = (unsigned int)__builtin_bit_cast(unsigned short, h);
    asm volatile("global_store_short %0, %1, off sc0 sc1" :: "v"(p), "v"(uv) : "memory");
}
// device-coherent 16B load (tail h read)
__device__ __forceinline__ u4v ld16_v(const void* p) {
    u4v r;
    asm volatile("global_load_dwordx4 %0, %1, off sc0 sc1\n\ts_waitcnt vmcnt(0)"
                 : "=v"(r) : "v"(p) : "memory");
    return r;
}
// write-through 16B store (h zero-init must land at coherent point)
__device__ __forceinline__ void st16_wt(void* p, u4v v) {
    asm volatile("global_store_dwordx4 %0, %1, off sc0 sc1" :: "v"(p), "v"(v) : "memory");
}

// embp[r][k] = k<100 ? (f16)emb[r][k] : 0   (10000 x 128)
__global__ void embp_kernel(const float* __restrict__ emb, _Float16* __restrict__ embp) {
    int r = blockIdx.x, k = threadIdx.x;
    embp[r * EPAD + k] = (k < EMBD) ? (_Float16)emb[r * EMBD + k] : (_Float16)0.f;
}

// wt[n][kp] = kp<K ? (f16)w[kp][n] : 0 ; wt row stride Kpad. block (32,8).
__global__ void tpad_kernel(const float* __restrict__ w, _Float16* __restrict__ wt,
                            int K, int Kpad, int N) {
    __shared__ float t[32][33];
    int k0 = blockIdx.x * 32, n0 = blockIdx.y * 32;
    int tx = threadIdx.x, ty = threadIdx.y;
    for (int i = ty; i < 32; i += 8) {
        int k = k0 + i;
        t[i][tx] = (k < K) ? w[(size_t)k * N + n0 + tx] : 0.f;
    }
    __syncthreads();
    for (int i = ty; i < 32; i += 8)
        wt[(size_t)(n0 + i) * Kpad + k0 + tx] = (_Float16)t[tx][i];
}

// blocks 0..2047: zero 8 MB H region WRITE-THROUGH; block 2048: zero sync words
__global__ void zero_kernel(char* __restrict__ p, unsigned* __restrict__ sync) {
    if (blockIdx.x == 2048) {
        if (threadIdx.x < 512)
            __hip_atomic_store(sync + threadIdx.x, 0u, __ATOMIC_RELAXED,
                               __HIP_MEMORY_SCOPE_AGENT);
        return;
    }
    u4v z = {0u, 0u, 0u, 0u};
    st16_wt(p + ((size_t)blockIdx.x * 256 + threadIdx.x) * 16, z);
}

// sync layout (u32 words): xcnt[g] at [g*16], root at [128], epoch[g] at [144+g*16]
struct PArgs {
    const int* x;            // [1024][80]
    const _Float16* EMBP;    // [10000][128]
    const _Float16* W0XT;    // [1024][128]
    const _Float16* W0HT;    // [1024][1024]
    const _Float16* W1XT;    // [1024][1024]
    const _Float16* W1HT;    // [1024][1024]
    const float* b0; const float* b1;
    _Float16* H00; _Float16* H01;   // h0 ping-pong
    _Float16* H10; _Float16* H11;   // h1 ping-pong
    const float* wout; const float* bout; float* out;
    unsigned* sync;
};

// 256 blocks x 512 threads. z = b>>7: 0 -> l1 task, 1 -> l0 task.
// Tile 64 rows x 128 cols; 8 waves each own a 64x16 col-strip.
// l1 (it>=1): h1_{it-1} = tanh(h0_{it-1}@W1x + h1_{it-2}@W1h + b1)
// l0 (it<SEQ): h0_it    = tanh(emb[x[:,it]]@W0x + h0_{it-1}@W0h + b0)
__launch_bounds__(512, 2)
__global__ void rnn_kernel(PArgs P) {
    __shared__ _Float16 As[4][64 * KC];   // 4 x 16 KB A-buffers (64 KB total)

    const int tid  = threadIdx.x;
    const int lane = tid & 63, w = tid >> 6;    // 8 waves
    const int quad = lane >> 4, l16 = lane & 15;

    const int b   = blockIdx.x;          // 0..255
    const int z   = b >> 7;              // 0: l1 (b 0..127), 1: l0 (b 128..255)
    const int bid = b & 127;
    const int row0 = (bid >> 3) * 64;    // 16 row-tiles
    const int col0 = (bid & 7) * 128;    // 8 col-tiles
    const int colw = col0 + w * 16 + l16;   // this lane's output column

    // A staging geometry (64 rows, KC=128, 8 waves -> 2 instr/wave):
    // instr g = w*2+q covers rows [g*4, g*4+4); lane l -> row r = g*4+(l>>4),
    // stored unit u' = l&15, logical unit u'^(r&7) (XOR-8 swizzle).
    int rrA[2], gofA[2], arA[2];
    #pragma unroll
    for (int q = 0; q < 2; ++q) {
        int g = w * 2 + q;
        int r = g * 4 + (lane >> 4);
        rrA[q]  = g * 512;                       // LDS halves
        gofA[q] = 8 * ((lane & 15) ^ (r & 7));   // swizzled k-offset (halves)
        arA[q]  = r;
    }

    // ---- register-resident B fragments: wb[ks] covers k = ks*32+quad*8 ----
    h8v wb[64];
    const int nch_ = z ? 9 : 16;         // KC=128 chunks (l0: 1 EMBP + 8 h0)
    if (z == 0) {                        // l1: K = [W1x (h0), W1h (h1)]
        const _Float16* wx = P.W1XT + (size_t)colw * UNITS + quad * 8;
        const _Float16* wh = P.W1HT + (size_t)colw * UNITS + quad * 8;
        #pragma unroll
        for (int ks = 0; ks < 32; ++ks) wb[ks]      = *(const h8v*)(wx + ks * 32);
        #pragma unroll
        for (int ks = 0; ks < 32; ++ks) wb[32 + ks] = *(const h8v*)(wh + ks * 32);
    } else {                             // l0: K = [W0x (emb 128), W0h (h0)]
        const _Float16* wx = P.W0XT + (size_t)colw * EPAD  + quad * 8;
        const _Float16* wh = P.W0HT + (size_t)colw * UNITS + quad * 8;
        #pragma unroll
        for (int ks = 0; ks < 4; ++ks)  wb[ks]     = *(const h8v*)(wx + ks * 32);
        #pragma unroll
        for (int ks = 0; ks < 32; ++ks) wb[4 + ks] = *(const h8v*)(wh + ks * 32);
    }

    _Float16* Hh0[2] = { P.H00, P.H01 };
    _Float16* Hh1[2] = { P.H10, P.H11 };
    const float* bias = z ? P.b0 : P.b1;

    unsigned* xcnt  = P.sync + (b & 7) * 16;
    unsigned* root  = P.sync + 128;
    unsigned* epoch = P.sync + 144 + (b & 7) * 16;

    for (int it = 0; it <= SEQ; ++it) {
        const int p = it & 1;
        const bool active = z ? (it < SEQ) : (it >= 1);
        if (active) {
            // A sources for this iteration (2 staging instrs/wave)
            const _Float16* a0p[2]; const _Float16* a1p[2];
            _Float16* outp;
            if (z) {                      // l0: A = [EMBP gather | h0_{it-1}]
                outp = Hh0[p];
                const _Float16* hb = Hh0[p ^ 1];
                #pragma unroll
                for (int q = 0; q < 2; ++q) {
                    int xi = P.x[(size_t)(row0 + arA[q]) * SEQ + it];
                    a0p[q] = P.EMBP + (size_t)xi * EPAD + gofA[q];
                    a1p[q] = hb + (size_t)(row0 + arA[q]) * UNITS + gofA[q];
                }
            } else {                      // l1: A = [h0_{it-1} | h1_{it-2}]
                outp = Hh1[p ^ 1];
                const _Float16* h0b = Hh0[p ^ 1];
                const _Float16* h1b = Hh1[p];
                #pragma unroll
                for (int q = 0; q < 2; ++q) {
                    a0p[q] = h0b + (size_t)(row0 + arA[q]) * UNITS + gofA[q];
                    a1p[q] = h1b + (size_t)(row0 + arA[q]) * UNITS + gofA[q];
                }
            }
            const int nsrc0 = z ? 1 : 8;  // chunks from source 0

            f4v acc[4] = {};

            auto issue = [&](int c) {
                const int buf = c & 3;
                #pragma unroll
                for (int q = 0; q < 2; ++q) {
                    if (c < nsrc0) {
                        if (z) gl_lds16_c(a0p[q] + c * KC, &As[buf][0] + rrA[q]);
                        else   gl_lds16_v(a0p[q] + c * KC, &As[buf][0] + rrA[q]);
                    } else {
                        gl_lds16_v(a1p[q] + (c - nsrc0) * KC, &As[buf][0] + rrA[q]);
                    }
                }
            };

            issue(0); issue(1); issue(2);          // 3-deep prologue
            #pragma unroll 1
            for (int c = 0; c < nch_; ++c) {
                const int cur = c & 3;
                const int rem = nch_ - 1 - c;      // chunks in flight beyond c
                if (rem >= 2)      asm volatile("s_waitcnt vmcnt(4)" ::: "memory");
                else if (rem == 1) asm volatile("s_waitcnt vmcnt(2)" ::: "memory");
                else               asm volatile("s_waitcnt vmcnt(0)" ::: "memory");
                __builtin_amdgcn_s_barrier();      // single barrier per chunk
                __builtin_amdgcn_sched_barrier(0);
                if (c + 3 < nch_) issue(c + 3);    // buf[(c+3)&3]=buf[(c-1)&3]
                #pragma unroll
                for (int kk = 0; kk < 4; ++kk) {
                    const int us = 8 * ((kk * 4 + quad) ^ (l16 & 7));
                    h8v af[4];
                    #pragma unroll
                    for (int m = 0; m < 4; ++m)
                        af[m] = *(const h8v*)(&As[cur][0] + (m * 16 + l16) * KC + us);
                    #pragma unroll
                    for (int m = 0; m < 4; ++m)
                        acc[m] = __builtin_amdgcn_mfma_f32_16x16x32_f16(
                            af[m], wb[c * 4 + kk], acc[m], 0, 0, 0);
                }
                __builtin_amdgcn_sched_barrier(0);
            }

            // epilogue: write-through device-coherent h stores
            {
                float bv = bias[colw];
                #pragma unroll
                for (int m = 0; m < 4; ++m) {
                    int r = row0 + m * 16 + quad * 4;
                    #pragma unroll
                    for (int g = 0; g < 4; ++g)
                        st2_wt(outp + (size_t)(r + g) * UNITS + colw,
                               tanh_fast(acc[m][g] + bv));
                }
            }
        }

        // ---- grid barrier: relaxed atomics only (no inv, no wbl2) ----
        const unsigned tgt = (unsigned)(it + 1);
        __syncthreads();                 // drains vmcnt(0): WT stores visible
        if (tid == 0) {
            unsigned r = __hip_atomic_fetch_add(xcnt, 1u, __ATOMIC_RELAXED,
                                                __HIP_MEMORY_SCOPE_AGENT);
            if ((r & 31u) == 31u)        // group of 32 complete -> promote
                __hip_atomic_fetch_add(root, 1u, __ATOMIC_RELAXED,
                                       __HIP_MEMORY_SCOPE_AGENT);
            if (b == 0) {
                while (__hip_atomic_load(root, __ATOMIC_RELAXED,
                                         __HIP_MEMORY_SCOPE_AGENT) < 8u * tgt)
                    __builtin_amdgcn_s_sleep(2);
                #pragma unroll
                for (int xx = 0; xx < 8; ++xx)
                    __hip_atomic_store(P.sync + 144 + xx * 16, tgt, __ATOMIC_RELAXED,
                                       __HIP_MEMORY_SCOPE_AGENT);
            }
            while (__hip_atomic_load(epoch, __ATOMIC_RELAXED,
                                     __HIP_MEMORY_SCOPE_AGENT) < tgt)
                __builtin_amdgcn_s_sleep(2);
        }
        __syncthreads();
    }

    // tail: out[row] = sigmoid(h1_79[row] . wout + bout); h1_79 = H11 (bypass)
    if (w < 4) {
        int row = b * 4 + w;
        const _Float16* hr = P.H11 + (size_t)row * UNITS;
        u4v d0 = ld16_v(hr + lane * 16);
        u4v d1 = ld16_v(hr + lane * 16 + 8);
        float sacc = 0.f;
        #pragma unroll
        for (int i = 0; i < 4; ++i) {
            unsigned w0 = d0[i], w1 = d1[i];
            _Float16 h0 = __builtin_bit_cast(_Float16, (unsigned short)(w0 & 0xffffu));
            _Float16 h1 = __builtin_bit_cast(_Float16, (unsigned short)(w0 >> 16));
            _Float16 h2 = __builtin_bit_cast(_Float16, (unsigned short)(w1 & 0xffffu));
            _Float16 h3 = __builtin_bit_cast(_Float16, (unsigned short)(w1 >> 16));
            sacc += (float)h0 * P.wout[lane * 16 + 2 * i + 0];
            sacc += (float)h1 * P.wout[lane * 16 + 2 * i + 1];
            sacc += (float)h2 * P.wout[lane * 16 + 8 + 2 * i + 0];
            sacc += (float)h3 * P.wout[lane * 16 + 8 + 2 * i + 1];
        }
        #pragma unroll
        for (int off = 32; off; off >>= 1) sacc += __shfl_down(sacc, off);
        if (lane == 0)
            P.out[row] = 1.f / (1.f + __expf(-(sacc + P.bout[0])));
    }
}

extern "C" void kernel_launch(void* const* d_in, const int* in_sizes, int n_in,
                              void* d_out, int out_size, void* d_ws, size_t ws_size,
                              hipStream_t stream) {
    const int*   x    = (const int*)d_in[0];
    const float* emb  = (const float*)d_in[1];
    const float* W0x  = (const float*)d_in[2];
    const float* W0h  = (const float*)d_in[3];
    const float* b0   = (const float*)d_in[4];
    const float* W1x  = (const float*)d_in[5];
    const float* W1h  = (const float*)d_in[6];
    const float* b1   = (const float*)d_in[7];
    const float* Wout = (const float*)d_in[8];
    const float* bout = (const float*)d_in[9];
    float* out = (float*)d_out;

    char* ws = (char*)d_ws;
    _Float16* EMBP = (_Float16*)ws;                          // 10000*128*2 = 2,560,000 B
    _Float16* W0XT = (_Float16*)(ws + 2560000);              // [1024][128]
    _Float16* W0HT = W0XT + 1024 * EPAD;                     // [1024][1024] x3
    _Float16* W1XT = W0HT + 1024 * 1024;
    _Float16* W1HT = W1XT + 1024 * 1024;
    _Float16* Hbuf = W1HT + 1024 * 1024;                     // 4 x 2 MB
    _Float16* H00 = Hbuf;
    _Float16* H01 = Hbuf + 1024 * 1024;
    _Float16* H10 = Hbuf + 2 * 1024 * 1024;
    _Float16* H11 = Hbuf + 3 * 1024 * 1024;
    unsigned* SYNC = (unsigned*)((char*)(Hbuf + 4 * 1024 * 1024));

    embp_kernel<<<10000, EPAD, 0, stream>>>(emb, EMBP);
    tpad_kernel<<<dim3(4, 32),  dim3(32, 8), 0, stream>>>(W0x, W0XT, EMBD, EPAD, UNITS);
    tpad_kernel<<<dim3(32, 32), dim3(32, 8), 0, stream>>>(W0h, W0HT, UNITS, UNITS, UNITS);
    tpad_kernel<<<dim3(32, 32), dim3(32, 8), 0, stream>>>(W1x, W1XT, UNITS, UNITS, UNITS);
    tpad_kernel<<<dim3(32, 32), dim3(32, 8), 0, stream>>>(W1h, W1HT, UNITS, UNITS, UNITS);
    zero_kernel<<<2049, 256, 0, stream>>>((char*)Hbuf, SYNC); // WT zeros + sync words

    PArgs P;
    P.x = x; P.EMBP = EMBP;
    P.W0XT = W0XT; P.W0HT = W0HT; P.W1XT = W1XT; P.W1HT = W1HT;
    P.b0 = b0; P.b1 = b1;
    P.H00 = H00; P.H01 = H01; P.H10 = H10; P.H11 = H11;
    P.wout = Wout; P.bout = bout; P.out = out;
    P.sync = SYNC;
    rnn_kernel<<<GRID, 512, 0, stream>>>(P);
}